// Round 1
// baseline (739.466 us; speedup 1.0000x reference)
//
#include <hip/hip_runtime.h>
#include <cstdint>

#define KF 100352   // 2048*49

typedef _Float16 half8 __attribute__((ext_vector_type(8)));
typedef float f32x4 __attribute__((ext_vector_type(4)));

__device__ __forceinline__ void async_copy16(void* lds, const void* g) {
  __builtin_amdgcn_global_load_lds(
      (const __attribute__((address_space(1))) void*)g,
      (__attribute__((address_space(3))) void*)lds, 16, 0, 0);
}

// ---------------- PE table + channel scale ----------------
// PEB[t*2048+c] = beta[c]*sqrt(2048) + pe[t,c];  Asc[c] = gamma[c]*sqrt(2048)/sqrt(1.00001)
__global__ __launch_bounds__(256) void pe_init(const float* __restrict__ gamma,
                                               const float* __restrict__ beta,
                                               float* __restrict__ PEB,
                                               float* __restrict__ Asc) {
  int idx = blockIdx.x * 256 + threadIdx.x;      // 0..65535
  int t = idx >> 11, c = idx & 2047;
  float freq = expf(-0.008994472042945492f * (float)c);   // 10000^(-2c/2048)
  float ang = (float)t * freq;
  float pe = (c & 1) ? cosf(ang) : sinf(ang);
  PEB[idx] = beta[c] * 45.254833995939045f + pe;
  if (idx < 2048) Asc[idx] = gamma[idx] * 45.254607729f;
}

// ---------------- fold BN+PE into x, store fp16 ----------------
__global__ __launch_bounds__(256) void prep_x(const float* __restrict__ x,
                                              const float* __restrict__ PEB,
                                              const float* __restrict__ Asc,
                                              _Float16* __restrict__ xh) {
  size_t i0 = ((size_t)blockIdx.x * 256 + threadIdx.x) * 8;
  float v[8];
  *(float4*)&v[0] = *(const float4*)(x + i0);
  *(float4*)&v[4] = *(const float4*)(x + i0 + 4);
  union { _Float16 o[8]; uint4 u; } U;
#pragma unroll
  for (int j = 0; j < 8; ++j) {
    unsigned idx = (unsigned)i0 + j;
    unsigned cm = idx / 49u;
    unsigned c = cm & 2047u;
    unsigned t = (cm >> 11) & 31u;
    U.o[j] = (_Float16)(v[j] * Asc[c] + PEB[(t << 11) + c]);
  }
  *(uint4*)(xh + i0) = U.u;
}

// ---------------- big GEMM: acc[m,o] += sum_k xh[m,k]*w[o,k] ----------------
// grid 512: nt = bid&7 (N tile of 128), kc = bid>>3 (K chunk of 1568). 512 threads.
__global__ __launch_bounds__(512, 2) void gemm_xq(const _Float16* __restrict__ xh,
                                                  const float* __restrict__ wq,
                                                  float* __restrict__ acc) {
  __shared__ __align__(16) _Float16 As[2 * 256 * 32];  // double-buffered A, 2x16KB
  __shared__ __align__(16) _Float16 Bs[128 * 32];      // 8KB

  const int tid = threadIdx.x;
  const int lane = tid & 63;
  const int wv = tid >> 6;   // 0..7
  const int wm = wv & 3;     // 64-row group
  const int wn = wv >> 2;    // 64-col group
  const int nt = blockIdx.x & 7;
  const int kc = blockIdx.x >> 3;
  const int o0 = nt * 128;
  const int kbase = kc * 1568;

  // A staging: per wave 2 issues of 16 rows (64 lanes * 16B = 16 rows * 64B)
  const int arow0 = (wv * 2 + 0) * 16 + (lane >> 2);
  const int arow1 = (wv * 2 + 1) * 16 + (lane >> 2);
  const _Float16* ag0 = xh + (size_t)arow0 * KF + kbase + (lane & 3) * 8;
  const _Float16* ag1 = xh + (size_t)arow1 * KF + kbase + (lane & 3) * 8;
  const int al0 = (wv * 2 + 0) * 512;
  const int al1 = (wv * 2 + 1) * 512;

  // B staging: thread -> (row o = tid>>2, 8 floats at part*8)
  const int bo = tid >> 2;
  const int bpart = tid & 3;
  const float* bg = wq + (size_t)(o0 + bo) * KF + kbase + bpart * 8;
  _Float16* blp = &Bs[bo * 32 + bpart * 8];

  f32x4 accv[4][4];
#pragma unroll
  for (int i = 0; i < 4; i++)
#pragma unroll
    for (int j = 0; j < 4; j++) accv[i][j] = (f32x4)0.f;

  const int aoff = (wm * 64 + (lane & 15)) * 32 + (lane >> 4) * 8;
  const int boff = (wn * 64 + (lane & 15)) * 32 + (lane >> 4) * 8;

  // prologue: step 0 in flight
  async_copy16(&As[al0], ag0);
  async_copy16(&As[al1], ag1);
  float4 b0 = *(const float4*)bg;
  float4 b1 = *(const float4*)(bg + 4);

  for (int s = 0; s < 49; ++s) {
    __syncthreads();  // A(s) arrived, B(s) regs drained, prior LDS reads done
    half8 bh;
    bh[0] = (_Float16)b0.x; bh[1] = (_Float16)b0.y;
    bh[2] = (_Float16)b0.z; bh[3] = (_Float16)b0.w;
    bh[4] = (_Float16)b1.x; bh[5] = (_Float16)b1.y;
    bh[6] = (_Float16)b1.z; bh[7] = (_Float16)b1.w;
    *(half8*)blp = bh;
    __syncthreads();  // B(s) visible; nothing else outstanding -> cheap drain
    if (s + 1 < 49) {
      const int kadv = (s + 1) * 32;
      const int nbuf = (s + 1) & 1;
      async_copy16(&As[nbuf * 8192 + al0], ag0 + kadv);  // overlaps compute(s)
      async_copy16(&As[nbuf * 8192 + al1], ag1 + kadv);
      b0 = *(const float4*)(bg + kadv);
      b1 = *(const float4*)(bg + kadv + 4);
    }
    const _Float16* Ab = &As[(s & 1) * 8192];
    half8 af[4], bf[4];
#pragma unroll
    for (int i = 0; i < 4; i++) af[i] = *(const half8*)(Ab + aoff + i * 512);
#pragma unroll
    for (int j = 0; j < 4; j++) bf[j] = *(const half8*)(&Bs[boff + j * 512]);
#pragma unroll
    for (int i = 0; i < 4; i++)
#pragma unroll
      for (int j = 0; j < 4; j++)
        accv[i][j] = __builtin_amdgcn_mfma_f32_16x16x32_f16(af[i], bf[j], accv[i][j], 0, 0, 0);
  }

  const int col = lane & 15;
  const int rq4 = (lane >> 4) * 4;
#pragma unroll
  for (int i = 0; i < 4; i++) {
    const int row = wm * 64 + i * 16 + rq4;
#pragma unroll
    for (int j = 0; j < 4; j++) {
      float* cp = acc + (size_t)row * 1024 + o0 + wn * 64 + j * 16 + col;
#pragma unroll
      for (int r = 0; r < 4; r++) unsafeAtomicAdd(cp + (size_t)r * 1024, accv[i][j][r]);
    }
  }
}

// ---------------- relu + layernorm(D=1024, ddof=1) ----------------
__global__ __launch_bounds__(256) void row_norm(const float* __restrict__ acc,
                                                float* __restrict__ xqn,
                                                float* __restrict__ curq) {
  const int m = blockIdx.x;
  const int tid = threadIdx.x;
  float4 v = *(const float4*)(acc + (size_t)m * 1024 + tid * 4);
  v.x = fmaxf(v.x, 0.f); v.y = fmaxf(v.y, 0.f);
  v.z = fmaxf(v.z, 0.f); v.w = fmaxf(v.w, 0.f);
  float s = v.x + v.y + v.z + v.w;
  float sq = v.x * v.x + v.y * v.y + v.z * v.z + v.w * v.w;
  const int lane = tid & 63, wvi = tid >> 6;
  for (int off = 32; off; off >>= 1) { s += __shfl_xor(s, off); sq += __shfl_xor(sq, off); }
  __shared__ float rs[4], rq[4];
  if (lane == 0) { rs[wvi] = s; rq[wvi] = sq; }
  __syncthreads();
  s = rs[0] + rs[1] + rs[2] + rs[3];
  sq = rq[0] + rq[1] + rq[2] + rq[3];
  float mu = s * (1.f / 1024.f);
  float var = fmaxf((sq - 1024.f * mu * mu) * (1.f / 1023.f), 0.f);
  float inv = 1.f / (sqrtf(var) + 1e-6f);
  float4 y;
  y.x = (v.x - mu) * inv; y.y = (v.y - mu) * inv;
  y.z = (v.z - mu) * inv; y.w = (v.w - mu) * inv;
  *(float4*)(xqn + (size_t)m * 1024 + tid * 4) = y;
  if ((m & 31) == 16) *(float4*)(curq + (size_t)(m >> 5) * 1024 + tid * 4) = y;
}

// ---------------- qh = relu(q @ qlin_w[it]^T + b), one output per wave ----------------
__global__ __launch_bounds__(256) void qh_kernel(const float* __restrict__ curq,
                                                 const float* __restrict__ qlw,
                                                 const float* __restrict__ qlb,
                                                 float* __restrict__ qh, int it) {
  const int gw = blockIdx.x * 4 + (threadIdx.x >> 6);  // 0..8191
  const int lane = threadIdx.x & 63;
  const int b = gw >> 10, o = gw & 1023;
  const float* wrow = qlw + ((size_t)it << 20) + (size_t)o * 1024;
  const float* qrow = curq + (size_t)b * 1024;
  float s = 0.f;
#pragma unroll
  for (int j = 0; j < 4; j++) {
    float4 qv = *(const float4*)(qrow + j * 256 + lane * 4);
    float4 wv = *(const float4*)(wrow + j * 256 + lane * 4);
    s += qv.x * wv.x + qv.y * wv.y + qv.z * wv.z + qv.w * wv.w;
  }
  for (int off = 32; off; off >>= 1) s += __shfl_xor(s, off);
  if (lane == 0) qh[(size_t)b * 1024 + o] = fmaxf(s + qlb[it * 1024 + o], 0.f);
}

// ---------------- one (b,h) attention+FF step, 64 threads ----------------
__global__ __launch_bounds__(64) void attn_kernel(
    const float* __restrict__ xqn, const float* __restrict__ qh,
    const float* __restrict__ n1a, const float* __restrict__ n1b,
    const float* __restrict__ n2a, const float* __restrict__ n2b,
    const float* __restrict__ fw1, const float* __restrict__ fb1,
    const float* __restrict__ fw2, const float* __restrict__ fb2,
    float* __restrict__ curq, int it) {
  const int bb = blockIdx.x >> 4;
  const int h = blockIdx.x & 15;
  const int lane = threadIdx.x;
  __shared__ float qhs[64], scs[32], es[32], qs[64], hids[32];

  const float* kbase = xqn + (size_t)bb * 32768 + h * 64;  // [t*1024 + dd]
  float qhd = qh[(size_t)bb * 1024 + h * 64 + lane];
  qhs[lane] = qhd;
  __syncthreads();
  if (lane < 32) {
    float s = 0.f;
    const float* kr = kbase + lane * 1024;
#pragma unroll 8
    for (int dd = 0; dd < 64; ++dd) s += qhs[dd] * kr[dd];
    scs[lane] = s * 0.125f;  // /sqrt(64)
  }
  __syncthreads();
  float mx = -1e30f;
  for (int t = 0; t < 32; t++) mx = fmaxf(mx, scs[t]);
  if (lane < 32) es[lane] = expf(scs[lane] - mx);
  __syncthreads();
  float den = 0.f, A = 0.f;
  for (int t = 0; t < 32; t++) { float e = es[t]; den += e; A += e * kbase[t * 1024 + lane]; }
  float z = A / den + qhd;
  // norm1 over 64 lanes, ddof=1
  float s = z, sq = z * z;
  for (int off = 32; off; off >>= 1) { s += __shfl_xor(s, off); sq += __shfl_xor(sq, off); }
  float mu = s * (1.f / 64.f);
  float var = fmaxf((sq - 64.f * mu * mu) * (1.f / 63.f), 0.f);
  float inv = 1.f / (sqrtf(var) + 1e-6f);
  const int nidx = it * 1024 + h * 64 + lane;
  float q_ = n1a[nidx] * (z - mu) * inv + n1b[nidx];
  qs[lane] = q_;
  __syncthreads();
  if (lane < 32) {
    const float* w1 = fw1 + ((size_t)(it * 16 + h) * 32 + lane) * 64;
    float a1 = fb1[(it * 16 + h) * 32 + lane];
#pragma unroll 8
    for (int dd = 0; dd < 64; ++dd) a1 += qs[dd] * w1[dd];
    hids[lane] = fmaxf(a1, 0.f);
  }
  __syncthreads();
  const float* w2 = fw2 + ((size_t)(it * 16 + h) * 64 + lane) * 32;
  float ffo = fb2[nidx];
#pragma unroll
  for (int f = 0; f < 32; ++f) ffo += hids[f] * w2[f];
  float z2 = q_ + ffo;
  float s2 = z2, sq2 = z2 * z2;
  for (int off = 32; off; off >>= 1) { s2 += __shfl_xor(s2, off); sq2 += __shfl_xor(sq2, off); }
  float mu2 = s2 * (1.f / 64.f);
  float var2 = fmaxf((sq2 - 64.f * mu2 * mu2) * (1.f / 63.f), 0.f);
  float inv2 = 1.f / (sqrtf(var2) + 1e-6f);
  curq[(size_t)bb * 1024 + h * 64 + lane] = n2a[nidx] * (z2 - mu2) * inv2 + n2b[nidx];
}

// ---------------- final L2 normalize ----------------
__global__ __launch_bounds__(256) void final_norm(const float* __restrict__ curq,
                                                  float* __restrict__ out) {
  const int b = blockIdx.x, tid = threadIdx.x;
  float4 v = *(const float4*)(curq + (size_t)b * 1024 + tid * 4);
  float sq = v.x * v.x + v.y * v.y + v.z * v.z + v.w * v.w;
  const int lane = tid & 63, wvi = tid >> 6;
  for (int off = 32; off; off >>= 1) sq += __shfl_xor(sq, off);
  __shared__ float rq[4];
  if (lane == 0) rq[wvi] = sq;
  __syncthreads();
  sq = rq[0] + rq[1] + rq[2] + rq[3];
  float inv = 1.f / fmaxf(sqrtf(sq), 1e-12f);
  float4 y; y.x = v.x * inv; y.y = v.y * inv; y.z = v.z * inv; y.w = v.w * inv;
  *(float4*)(out + (size_t)b * 1024 + tid * 4) = y;
}

extern "C" void kernel_launch(void* const* d_in, const int* in_sizes, int n_in,
                              void* d_out, int out_size, void* d_ws, size_t ws_size,
                              hipStream_t stream) {
  const float* x     = (const float*)d_in[0];
  const float* gamma = (const float*)d_in[1];
  const float* beta  = (const float*)d_in[2];
  const float* qpr   = (const float*)d_in[3];
  const float* qlw   = (const float*)d_in[4];
  const float* qlb   = (const float*)d_in[5];
  const float* n1a   = (const float*)d_in[6];
  const float* n1b   = (const float*)d_in[7];
  const float* n2a   = (const float*)d_in[8];
  const float* n2b   = (const float*)d_in[9];
  const float* fw1   = (const float*)d_in[10];
  const float* fb1   = (const float*)d_in[11];
  const float* fw2   = (const float*)d_in[12];
  const float* fb2   = (const float*)d_in[13];

  char* ws = (char*)d_ws;
  _Float16* xh = (_Float16*)ws;                 // 51,380,224 B
  float* acc  = (float*)(ws + 51380224);        // 1 MB
  float* xqn  = (float*)(ws + 52428800);        // 1 MB
  float* PEB  = (float*)(ws + 53477376);        // 256 KB
  float* Asc  = (float*)(ws + 53739520);        // 8 KB
  float* curq = (float*)(ws + 53747712);        // 32 KB
  float* qh   = (float*)(ws + 53780480);        // 32 KB

  hipMemsetAsync(acc, 0, 1024 * 1024, stream);
  pe_init<<<256, 256, 0, stream>>>(gamma, beta, PEB, Asc);
  prep_x<<<12544, 256, 0, stream>>>(x, PEB, Asc, xh);
  gemm_xq<<<512, 512, 0, stream>>>(xh, qpr, acc);
  row_norm<<<256, 256, 0, stream>>>(acc, xqn, curq);
  for (int it = 0; it < 3; ++it) {
    qh_kernel<<<2048, 256, 0, stream>>>(curq, qlw, qlb, qh, it);
    attn_kernel<<<128, 64, 0, stream>>>(xqn, qh, n1a, n1b, n2a, n2b,
                                        fw1, fb1, fw2, fb2, curq, it);
  }
  final_norm<<<8, 256, 0, stream>>>(curq, (float*)d_out);
}

// Round 2
// 723.287 us; speedup vs baseline: 1.0224x; 1.0224x over previous
//
#include <hip/hip_runtime.h>
#include <cstdint>

#define KF 100352   // 2048*49

typedef _Float16 half8 __attribute__((ext_vector_type(8)));
typedef float f32x4 __attribute__((ext_vector_type(4)));

__device__ __forceinline__ void async_copy16(void* lds, const void* g) {
  __builtin_amdgcn_global_load_lds(
      (const __attribute__((address_space(1))) void*)g,
      (__attribute__((address_space(3))) void*)lds, 16, 0, 0);
}

// ---------------- PE table + channel scale ----------------
__global__ __launch_bounds__(256) void pe_init(const float* __restrict__ gamma,
                                               const float* __restrict__ beta,
                                               float* __restrict__ PEB,
                                               float* __restrict__ Asc) {
  int idx = blockIdx.x * 256 + threadIdx.x;      // 0..65535
  int t = idx >> 11, c = idx & 2047;
  float freq = expf(-0.008994472042945492f * (float)c);   // 10000^(-2c/2048)
  float ang = (float)t * freq;
  float pe = (c & 1) ? cosf(ang) : sinf(ang);
  PEB[idx] = beta[c] * 45.254833995939045f + pe;
  if (idx < 2048) Asc[idx] = gamma[idx] * 45.254607729f;
}

// ---------------- fold BN+PE into x, store fp16 ----------------
__global__ __launch_bounds__(256) void prep_x(const float* __restrict__ x,
                                              const float* __restrict__ PEB,
                                              const float* __restrict__ Asc,
                                              _Float16* __restrict__ xh) {
  size_t i0 = ((size_t)blockIdx.x * 256 + threadIdx.x) * 8;
  float v[8];
  *(float4*)&v[0] = *(const float4*)(x + i0);
  *(float4*)&v[4] = *(const float4*)(x + i0 + 4);
  union { _Float16 o[8]; uint4 u; } U;
#pragma unroll
  for (int j = 0; j < 8; ++j) {
    unsigned idx = (unsigned)i0 + j;
    unsigned cm = idx / 49u;
    unsigned c = cm & 2047u;
    unsigned t = (cm >> 11) & 31u;
    U.o[j] = (_Float16)(v[j] * Asc[c] + PEB[(t << 11) + c]);
  }
  *(uint4*)(xh + i0) = U.u;
}

// ---------------- big GEMM: part[kc][m][o] = sum_k xh[m,k]*w[o,k] over k-chunk ----------------
// grid 512: nt = bid&7 (N tile of 128), kc = bid>>3 (K chunk of 1568). 512 threads.
__global__ __launch_bounds__(512, 4) void gemm_xq(const _Float16* __restrict__ xh,
                                                  const float* __restrict__ wq,
                                                  float* __restrict__ part) {
  __shared__ __align__(16) _Float16 As[2 * 256 * 32];  // double-buffered A, 2x16KB
  __shared__ __align__(16) _Float16 Bs[128 * 32];      // 8KB

  const int tid = threadIdx.x;
  const int lane = tid & 63;
  const int wv = tid >> 6;   // 0..7
  const int wm = wv & 3;     // 64-row group
  const int wn = wv >> 2;    // 64-col group
  const int nt = blockIdx.x & 7;
  const int kc = blockIdx.x >> 3;
  const int o0 = nt * 128;
  const int kbase = kc * 1568;

  // A staging: per wave 2 issues of 16 rows (64 lanes * 16B = 16 rows * 64B)
  const int arow0 = (wv * 2 + 0) * 16 + (lane >> 2);
  const int arow1 = (wv * 2 + 1) * 16 + (lane >> 2);
  const _Float16* ag0 = xh + (size_t)arow0 * KF + kbase + (lane & 3) * 8;
  const _Float16* ag1 = xh + (size_t)arow1 * KF + kbase + (lane & 3) * 8;
  const int al0 = (wv * 2 + 0) * 512;
  const int al1 = (wv * 2 + 1) * 512;

  // B staging: thread -> (row o = tid>>2, 8 floats at part*8)
  const int bo = tid >> 2;
  const int bpart = tid & 3;
  const float* bg = wq + (size_t)(o0 + bo) * KF + kbase + bpart * 8;
  _Float16* blp = &Bs[bo * 32 + bpart * 8];

  f32x4 accv[4][4];
#pragma unroll
  for (int i = 0; i < 4; i++)
#pragma unroll
    for (int j = 0; j < 4; j++) accv[i][j] = (f32x4)0.f;

  const int aoff = (wm * 64 + (lane & 15)) * 32 + (lane >> 4) * 8;
  const int boff = (wn * 64 + (lane & 15)) * 32 + (lane >> 4) * 8;

  // prologue: step 0 in flight
  async_copy16(&As[al0], ag0);
  async_copy16(&As[al1], ag1);
  float4 b0 = *(const float4*)bg;
  float4 b1 = *(const float4*)(bg + 4);

  for (int s = 0; s < 49; ++s) {
    __syncthreads();  // A(s) arrived, B(s) regs drained, prior LDS reads done
    half8 bh;
    bh[0] = (_Float16)b0.x; bh[1] = (_Float16)b0.y;
    bh[2] = (_Float16)b0.z; bh[3] = (_Float16)b0.w;
    bh[4] = (_Float16)b1.x; bh[5] = (_Float16)b1.y;
    bh[6] = (_Float16)b1.z; bh[7] = (_Float16)b1.w;
    *(half8*)blp = bh;
    __syncthreads();  // B(s) visible
    if (s + 1 < 49) {
      const int kadv = (s + 1) * 32;
      const int nbuf = (s + 1) & 1;
      async_copy16(&As[nbuf * 8192 + al0], ag0 + kadv);  // overlaps compute(s)
      async_copy16(&As[nbuf * 8192 + al1], ag1 + kadv);
      b0 = *(const float4*)(bg + kadv);
      b1 = *(const float4*)(bg + kadv + 4);
    }
    const _Float16* Ab = &As[(s & 1) * 8192];
    half8 af[4], bf[4];
#pragma unroll
    for (int i = 0; i < 4; i++) af[i] = *(const half8*)(Ab + aoff + i * 512);
#pragma unroll
    for (int j = 0; j < 4; j++) bf[j] = *(const half8*)(&Bs[boff + j * 512]);
#pragma unroll
    for (int i = 0; i < 4; i++)
#pragma unroll
      for (int j = 0; j < 4; j++)
        accv[i][j] = __builtin_amdgcn_mfma_f32_16x16x32_f16(af[i], bf[j], accv[i][j], 0, 0, 0);
  }

  // epilogue: plain streaming stores to this kc's private partial slice
  float* pslice = part + (size_t)kc * (256 * 1024);
  const int col = lane & 15;
  const int rq4 = (lane >> 4) * 4;
#pragma unroll
  for (int i = 0; i < 4; i++) {
    const int row = wm * 64 + i * 16 + rq4;
#pragma unroll
    for (int j = 0; j < 4; j++) {
      float* cp = pslice + (size_t)row * 1024 + o0 + wn * 64 + j * 16 + col;
#pragma unroll
      for (int r = 0; r < 4; r++) cp[(size_t)r * 1024] = accv[i][j][r];
    }
  }
}

// ---------------- reduce 64 k-chunk partials -> acc ----------------
__global__ __launch_bounds__(256) void reduce_acc(const float* __restrict__ part,
                                                  float* __restrict__ acc) {
  const size_t o4 = ((size_t)blockIdx.x * 256 + threadIdx.x);  // float4 index, 65536 total
  const float* p = part + o4 * 4;
  float4 s = *(const float4*)p;
#pragma unroll 9
  for (int kc = 1; kc < 64; ++kc) {
    float4 v = *(const float4*)(p + (size_t)kc * 262144);
    s.x += v.x; s.y += v.y; s.z += v.z; s.w += v.w;
  }
  *(float4*)(acc + o4 * 4) = s;
}

// ---------------- relu + layernorm(D=1024, ddof=1) ----------------
__global__ __launch_bounds__(256) void row_norm(const float* __restrict__ acc,
                                                float* __restrict__ xqn,
                                                float* __restrict__ curq) {
  const int m = blockIdx.x;
  const int tid = threadIdx.x;
  float4 v = *(const float4*)(acc + (size_t)m * 1024 + tid * 4);
  v.x = fmaxf(v.x, 0.f); v.y = fmaxf(v.y, 0.f);
  v.z = fmaxf(v.z, 0.f); v.w = fmaxf(v.w, 0.f);
  float s = v.x + v.y + v.z + v.w;
  float sq = v.x * v.x + v.y * v.y + v.z * v.z + v.w * v.w;
  const int lane = tid & 63, wvi = tid >> 6;
  for (int off = 32; off; off >>= 1) { s += __shfl_xor(s, off); sq += __shfl_xor(sq, off); }
  __shared__ float rs[4], rq[4];
  if (lane == 0) { rs[wvi] = s; rq[wvi] = sq; }
  __syncthreads();
  s = rs[0] + rs[1] + rs[2] + rs[3];
  sq = rq[0] + rq[1] + rq[2] + rq[3];
  float mu = s * (1.f / 1024.f);
  float var = fmaxf((sq - 1024.f * mu * mu) * (1.f / 1023.f), 0.f);
  float inv = 1.f / (sqrtf(var) + 1e-6f);
  float4 y;
  y.x = (v.x - mu) * inv; y.y = (v.y - mu) * inv;
  y.z = (v.z - mu) * inv; y.w = (v.w - mu) * inv;
  *(float4*)(xqn + (size_t)m * 1024 + tid * 4) = y;
  if ((m & 31) == 16) *(float4*)(curq + (size_t)(m >> 5) * 1024 + tid * 4) = y;
}

// ---------------- qh = relu(q @ qlin_w[it]^T + b), one output per wave ----------------
__global__ __launch_bounds__(256) void qh_kernel(const float* __restrict__ curq,
                                                 const float* __restrict__ qlw,
                                                 const float* __restrict__ qlb,
                                                 float* __restrict__ qh, int it) {
  const int gw = blockIdx.x * 4 + (threadIdx.x >> 6);  // 0..8191
  const int lane = threadIdx.x & 63;
  const int b = gw >> 10, o = gw & 1023;
  const float* wrow = qlw + ((size_t)it << 20) + (size_t)o * 1024;
  const float* qrow = curq + (size_t)b * 1024;
  float s = 0.f;
#pragma unroll
  for (int j = 0; j < 4; j++) {
    float4 qv = *(const float4*)(qrow + j * 256 + lane * 4);
    float4 wv = *(const float4*)(wrow + j * 256 + lane * 4);
    s += qv.x * wv.x + qv.y * wv.y + qv.z * wv.z + qv.w * wv.w;
  }
  for (int off = 32; off; off >>= 1) s += __shfl_xor(s, off);
  if (lane == 0) qh[(size_t)b * 1024 + o] = fmaxf(s + qlb[it * 1024 + o], 0.f);
}

// ---------------- one (b,h) attention+FF step, 64 threads ----------------
__global__ __launch_bounds__(64) void attn_kernel(
    const float* __restrict__ xqn, const float* __restrict__ qh,
    const float* __restrict__ n1a, const float* __restrict__ n1b,
    const float* __restrict__ n2a, const float* __restrict__ n2b,
    const float* __restrict__ fw1, const float* __restrict__ fb1,
    const float* __restrict__ fw2, const float* __restrict__ fb2,
    float* __restrict__ curq, int it) {
  const int bb = blockIdx.x >> 4;
  const int h = blockIdx.x & 15;
  const int lane = threadIdx.x;
  __shared__ float qhs[64], scs[32], es[32], qs[64], hids[32];

  const float* kbase = xqn + (size_t)bb * 32768 + h * 64;  // [t*1024 + dd]
  float qhd = qh[(size_t)bb * 1024 + h * 64 + lane];
  qhs[lane] = qhd;
  __syncthreads();
  if (lane < 32) {
    float s = 0.f;
    const float* kr = kbase + lane * 1024;
#pragma unroll 8
    for (int dd = 0; dd < 64; ++dd) s += qhs[dd] * kr[dd];
    scs[lane] = s * 0.125f;  // /sqrt(64)
  }
  __syncthreads();
  float mx = -1e30f;
  for (int t = 0; t < 32; t++) mx = fmaxf(mx, scs[t]);
  if (lane < 32) es[lane] = expf(scs[lane] - mx);
  __syncthreads();
  float den = 0.f, A = 0.f;
  for (int t = 0; t < 32; t++) { float e = es[t]; den += e; A += e * kbase[t * 1024 + lane]; }
  float z = A / den + qhd;
  float s = z, sq = z * z;
  for (int off = 32; off; off >>= 1) { s += __shfl_xor(s, off); sq += __shfl_xor(sq, off); }
  float mu = s * (1.f / 64.f);
  float var = fmaxf((sq - 64.f * mu * mu) * (1.f / 63.f), 0.f);
  float inv = 1.f / (sqrtf(var) + 1e-6f);
  const int nidx = it * 1024 + h * 64 + lane;
  float q_ = n1a[nidx] * (z - mu) * inv + n1b[nidx];
  qs[lane] = q_;
  __syncthreads();
  if (lane < 32) {
    const float* w1 = fw1 + ((size_t)(it * 16 + h) * 32 + lane) * 64;
    float a1 = fb1[(it * 16 + h) * 32 + lane];
#pragma unroll 8
    for (int dd = 0; dd < 64; ++dd) a1 += qs[dd] * w1[dd];
    hids[lane] = fmaxf(a1, 0.f);
  }
  __syncthreads();
  const float* w2 = fw2 + ((size_t)(it * 16 + h) * 64 + lane) * 32;
  float ffo = fb2[nidx];
#pragma unroll
  for (int f = 0; f < 32; ++f) ffo += hids[f] * w2[f];
  float z2 = q_ + ffo;
  float s2 = z2, sq2 = z2 * z2;
  for (int off = 32; off; off >>= 1) { s2 += __shfl_xor(s2, off); sq2 += __shfl_xor(sq2, off); }
  float mu2 = s2 * (1.f / 64.f);
  float var2 = fmaxf((sq2 - 64.f * mu2 * mu2) * (1.f / 63.f), 0.f);
  float inv2 = 1.f / (sqrtf(var2) + 1e-6f);
  curq[(size_t)bb * 1024 + h * 64 + lane] = n2a[nidx] * (z2 - mu2) * inv2 + n2b[nidx];
}

// ---------------- final L2 normalize ----------------
__global__ __launch_bounds__(256) void final_norm(const float* __restrict__ curq,
                                                  float* __restrict__ out) {
  const int b = blockIdx.x, tid = threadIdx.x;
  float4 v = *(const float4*)(curq + (size_t)b * 1024 + tid * 4);
  float sq = v.x * v.x + v.y * v.y + v.z * v.z + v.w * v.w;
  const int lane = tid & 63, wvi = tid >> 6;
  for (int off = 32; off; off >>= 1) sq += __shfl_xor(sq, off);
  __shared__ float rq[4];
  if (lane == 0) rq[wvi] = sq;
  __syncthreads();
  sq = rq[0] + rq[1] + rq[2] + rq[3];
  float inv = 1.f / fmaxf(sqrtf(sq), 1e-12f);
  float4 y; y.x = v.x * inv; y.y = v.y * inv; y.z = v.z * inv; y.w = v.w * inv;
  *(float4*)(out + (size_t)b * 1024 + tid * 4) = y;
}

extern "C" void kernel_launch(void* const* d_in, const int* in_sizes, int n_in,
                              void* d_out, int out_size, void* d_ws, size_t ws_size,
                              hipStream_t stream) {
  const float* x     = (const float*)d_in[0];
  const float* gamma = (const float*)d_in[1];
  const float* beta  = (const float*)d_in[2];
  const float* qpr   = (const float*)d_in[3];
  const float* qlw   = (const float*)d_in[4];
  const float* qlb   = (const float*)d_in[5];
  const float* n1a   = (const float*)d_in[6];
  const float* n1b   = (const float*)d_in[7];
  const float* n2a   = (const float*)d_in[8];
  const float* n2b   = (const float*)d_in[9];
  const float* fw1   = (const float*)d_in[10];
  const float* fb1   = (const float*)d_in[11];
  const float* fw2   = (const float*)d_in[12];
  const float* fb2   = (const float*)d_in[13];

  char* ws = (char*)d_ws;
  _Float16* xh = (_Float16*)ws;                   // 51,380,224 B
  float* part = (float*)(ws + 51380224);          // 64 MB (64 x 256 x 1024 fp32)
  float* acc  = (float*)(ws + 51380224 + 67108864);            // 1 MB
  float* xqn  = (float*)(ws + 51380224 + 67108864 + 1048576);  // 1 MB
  float* PEB  = (float*)(ws + 51380224 + 67108864 + 2097152);  // 256 KB
  float* Asc  = (float*)(ws + 51380224 + 67108864 + 2359296);  // 8 KB
  float* curq = (float*)(ws + 51380224 + 67108864 + 2367488);  // 32 KB
  float* qh   = (float*)(ws + 51380224 + 67108864 + 2400256);  // 32 KB

  pe_init<<<256, 256, 0, stream>>>(gamma, beta, PEB, Asc);
  prep_x<<<12544, 256, 0, stream>>>(x, PEB, Asc, xh);
  gemm_xq<<<512, 512, 0, stream>>>(xh, qpr, part);
  reduce_acc<<<256, 256, 0, stream>>>(part, acc);
  row_norm<<<256, 256, 0, stream>>>(acc, xqn, curq);
  for (int it = 0; it < 3; ++it) {
    qh_kernel<<<2048, 256, 0, stream>>>(curq, qlw, qlb, qh, it);
    attn_kernel<<<128, 64, 0, stream>>>(xqn, qh, n1a, n1b, n2a, n2b,
                                        fw1, fb1, fw2, fb2, curq, it);
  }
  final_norm<<<8, 256, 0, stream>>>(curq, (float*)d_out);
}